// Round 1
// 643.731 us; speedup vs baseline: 1.0880x; 1.0880x over previous
//
#include <hip/hip_runtime.h>

#define BATCH 16
#define CIN   512
#define COUT  512
#define HDIM  64
#define HW    4096
#define STY   512
#define NTAP  9
// 1/sqrt(512*9)
#define SCALE 0.014731391274719739f

typedef __bf16 bf16x8 __attribute__((ext_vector_type(8)));
typedef float  f32x4  __attribute__((ext_vector_type(4)));

static __device__ __forceinline__ unsigned short f2bf(float f) {
  union { float f; unsigned u; } v; v.f = f;
  unsigned u = v.u;
  u += 0x7fffu + ((u >> 16) & 1u);   // RNE; inputs finite
  return (unsigned short)(u >> 16);
}
static __device__ __forceinline__ float bf2f(unsigned short h) {
  union { unsigned u; float f; } v; v.u = ((unsigned)h) << 16;
  return v.f;
}

// S[b][ci] = SCALE * (sum_j style[b][j]*mod_w[ci][j] + mod_b[ci])
__global__ void k_style(const float* __restrict__ style, const float* __restrict__ mod_w,
                        const float* __restrict__ mod_b, float* __restrict__ S) {
  __shared__ __align__(16) float sty[STY];
  int b = blockIdx.x;
  for (int j = threadIdx.x; j < STY; j += 256) sty[j] = style[b*STY + j];
  __syncthreads();
  for (int ci = threadIdx.x; ci < CIN; ci += 256) {
    const float4* wr = reinterpret_cast<const float4*>(mod_w + ci*STY);
    const float4* sr = reinterpret_cast<const float4*>(sty);
    float acc = 0.f;
    #pragma unroll 4
    for (int j = 0; j < STY/4; ++j) {
      float4 w = wr[j], s = sr[j];
      acc += w.x*s.x + w.y*s.y + w.z*s.z + w.w*s.w;
    }
    S[b*CIN + ci] = SCALE * (acc + mod_b[ci]);
  }
}

// wsq[co][ci] = sum_tap weight^2 ; wpack[tap][co][ci] = bf16(weight) (tap-major repack)
__global__ void k_wsq_pack(const float* __restrict__ weight, float* __restrict__ wsq,
                           unsigned short* __restrict__ wpack) {
  int co = blockIdx.x;
  for (int ci = threadIdx.x; ci < CIN; ci += 256) {
    const float* wp = weight + (co*CIN + ci)*NTAP;
    float ssq = 0.f;
    #pragma unroll
    for (int t = 0; t < NTAP; ++t) {
      float w = wp[t];
      ssq += w * w;
      wpack[(t*COUT + co)*CIN + ci] = f2bf(w);
    }
    wsq[co*CIN + ci] = ssq;
  }
}

// D[b][co] = rsqrt(sum_ci S^2 * wsq + eps); one wave per (b,co)
__global__ void k_demod(const float* __restrict__ S, const float* __restrict__ wsq,
                        float* __restrict__ D) {
  int wid  = blockIdx.x * 4 + (threadIdx.x >> 6);  // b*512 + co
  int lane = threadIdx.x & 63;
  int b  = wid >> 9;
  int co = wid & 511;
  float sum = 0.f;
  #pragma unroll
  for (int i = 0; i < CIN/64; ++i) {
    int ci = lane + i*64;
    float s = S[b*CIN + ci];
    sum += s * s * wsq[co*CIN + ci];
  }
  #pragma unroll
  for (int off = 32; off > 0; off >>= 1) sum += __shfl_down(sum, off);
  if (lane == 0) D[b*COUT + co] = rsqrtf(sum + 1e-8f);
}

// Main conv: per (b, co-tile 128, pixel-tile 128 = 2 image rows) block.
// Modulation folded in: B-side staged as bf16(x * S[b,ci]); A-side is the
// batch-independent bf16 weight pack; demod D[b,co] applied in f32 epilogue.
// K-loop: ci chunks of 32 (halo input staged once/chunk), inner 9 taps (A staged/tap).
#define APAD 40
#define BPAD 40
__global__ __launch_bounds__(256) void k_conv(const float* __restrict__ in,
                                              const unsigned short* __restrict__ wpack,
                                              const float* __restrict__ S,
                                              const float* __restrict__ D,
                                              float* __restrict__ out) {
  const int b   = blockIdx.z;
  const int co0 = blockIdx.y * 128;
  const int pt  = blockIdx.x;
  const int h0  = pt * 2;

  const int tid  = threadIdx.x;
  const int lane = tid & 63;
  const int wave = tid >> 6;
  const int wm   = wave >> 1;       // co half of tile
  const int wn   = wave & 1;        // pixel half
  const int l15  = lane & 15;
  const int quad = lane >> 4;

  __shared__ __align__(16) unsigned short As[128 * APAD];     // [co][ci], pad->40
  __shared__ __align__(16) unsigned short Bs[4 * 66 * BPAD];  // [halo row][halo col][ci], pad->40

  f32x4 zero = {0.f, 0.f, 0.f, 0.f};
  f32x4 acc[4][4];
  #pragma unroll
  for (int i = 0; i < 4; ++i)
    #pragma unroll
    for (int j = 0; j < 4; ++j) acc[i][j] = zero;

  const float* inb = in + b * (CIN * HW);

  // halo columns 0 and 65 (image w=-1,64) are always zero; write once
  if (tid < 32) {
    int row = tid >> 3, rem = tid & 7;
    int ch  = (rem >> 2) * 65;
    int ci8 = (rem & 3) * 8;
    uint4 z = {0u, 0u, 0u, 0u};
    *reinterpret_cast<uint4*>(&Bs[(row*66 + ch)*BPAD + ci8]) = z;
  }

  // frag read offsets (elements)
  int a_off[4], b_base[4];
  #pragma unroll
  for (int mt = 0; mt < 4; ++mt) a_off[mt] = (wm*64 + mt*16 + l15) * APAD + quad*8;
  #pragma unroll
  for (int nt = 0; nt < 4; ++nt) {
    int px = wn*64 + nt*16 + l15;   // 0..127 within tile
    int r = px >> 6, c = px & 63;
    b_base[nt] = (r*66 + c) * BPAD + quad*8;  // + ((kh*66+kw)*BPAD) per tap
  }

  const int scol = tid & 63;   // image col this thread stages
  const int srow = tid >> 6;   // halo row (wave-uniform)

  #pragma unroll 1
  for (int ci0 = 0; ci0 < CIN; ci0 += 32) {
    // ---- stage B halo: rows h0-1..h0+2, cols 0..63 (halo col+1), 32 ci ----
    // modulation fold: each staged element is x * S[b, ci]  (S is wave-uniform)
    {
      int g = h0 - 1 + srow;
      bool inr = (g >= 0) && (g < HDIM);
      const float* src = inb + ci0*HW + g*HDIM + scol;
      const float4* Sb4 = reinterpret_cast<const float4*>(S + b*CIN + ci0);
      #pragma unroll
      for (int cg = 0; cg < 4; ++cg) {
        float4 s0 = Sb4[cg*2];
        float4 s1 = Sb4[cg*2 + 1];
        float sv[8] = {s0.x, s0.y, s0.z, s0.w, s1.x, s1.y, s1.z, s1.w};
        unsigned short h[8];
        #pragma unroll
        for (int j = 0; j < 8; ++j) {
          float v = inr ? src[(cg*8 + j)*HW] : 0.f;
          h[j] = f2bf(v * sv[j]);
        }
        uint4 pk;
        pk.x = (unsigned)h[0] | ((unsigned)h[1] << 16);
        pk.y = (unsigned)h[2] | ((unsigned)h[3] << 16);
        pk.z = (unsigned)h[4] | ((unsigned)h[5] << 16);
        pk.w = (unsigned)h[6] | ((unsigned)h[7] << 16);
        *reinterpret_cast<uint4*>(&Bs[(srow*66 + scol + 1)*BPAD + cg*8]) = pk;
      }
    }
    #pragma unroll 1
    for (int tap = 0; tap < NTAP; ++tap) {
      // ---- stage A: wpack[tap][co0..+128][ci0..+32], 2x16B per thread ----
      const unsigned short* asrc = wpack + (tap*COUT + co0)*CIN + ci0;
      #pragma unroll
      for (int it = 0; it < 2; ++it) {
        int idx = tid + it*256;
        int row = idx >> 2, q = idx & 3;
        uint4 v = *reinterpret_cast<const uint4*>(asrc + row*CIN + q*8);
        *reinterpret_cast<uint4*>(&As[row*APAD + q*8]) = v;
      }
      __syncthreads();
      const int toff = ((tap/3)*66 + (tap%3)) * BPAD;
      bf16x8 af[4], bfr[4];
      #pragma unroll
      for (int mt = 0; mt < 4; ++mt) {
        uint4 raw = *reinterpret_cast<const uint4*>(&As[a_off[mt]]);
        af[mt] = __builtin_bit_cast(bf16x8, raw);
      }
      #pragma unroll
      for (int nt = 0; nt < 4; ++nt) {
        uint4 raw = *reinterpret_cast<const uint4*>(&Bs[b_base[nt] + toff]);
        bfr[nt] = __builtin_bit_cast(bf16x8, raw);
      }
      #pragma unroll
      for (int mt = 0; mt < 4; ++mt)
        #pragma unroll
        for (int nt = 0; nt < 4; ++nt)
          acc[mt][nt] = __builtin_amdgcn_mfma_f32_16x16x32_bf16(af[mt], bfr[nt], acc[mt][nt], 0, 0, 0);
      __syncthreads();   // protect As (next tap) / Bs (next chunk)
    }
  }

  // epilogue: C/D layout col=lane&15 (pixel), row=quad*4+reg (co); apply demod here
  #pragma unroll
  for (int mt = 0; mt < 4; ++mt) {
    int co = co0 + wm*64 + mt*16 + quad*4;
    float dvr[4];
    #pragma unroll
    for (int r = 0; r < 4; ++r) dvr[r] = D[b*COUT + co + r];
    #pragma unroll
    for (int nt = 0; nt < 4; ++nt) {
      int px = pt*128 + wn*64 + nt*16 + l15;
      float* op = out + (b*COUT + co)*HW + px;
      #pragma unroll
      for (int r = 0; r < 4; ++r) op[r*HW] = acc[mt][nt][r] * dvr[r];
    }
  }
}

extern "C" void kernel_launch(void* const* d_in, const int* in_sizes, int n_in,
                              void* d_out, int out_size, void* d_ws, size_t ws_size,
                              hipStream_t stream) {
  const float* input  = (const float*)d_in[0];
  const float* style  = (const float*)d_in[1];
  const float* weight = (const float*)d_in[2];
  const float* mod_w  = (const float*)d_in[3];
  const float* mod_b  = (const float*)d_in[4];
  float* out = (float*)d_out;

  char* ws = (char*)d_ws;
  float* S = (float*)ws;                                   //    32 KB
  float* D = (float*)(ws + 32768);                         //    32 KB
  float* wsq = (float*)(ws + 65536);                       //     1 MB
  unsigned short* wpack = (unsigned short*)(ws + 65536 + 1048576);  // 4.72 MB
  // total ws need: 5,832,704 bytes (wmod eliminated — modulation folded into k_conv)

  k_style<<<BATCH, 256, 0, stream>>>(style, mod_w, mod_b, S);
  k_wsq_pack<<<COUT, 256, 0, stream>>>(weight, wsq, wpack);
  k_demod<<<(BATCH*COUT)/4, 256, 0, stream>>>(S, wsq, D);

  dim3 grid(HW/128, COUT/128, BATCH);
  k_conv<<<grid, 256, 0, stream>>>(input, wpack, S, D, out);
}